// Round 18
// baseline (208.195 us; speedup 1.0000x reference)
//
#include <hip/hip_runtime.h>

typedef unsigned short u16;
typedef unsigned int u32;
typedef __attribute__((ext_vector_type(8))) short bf16x8;
typedef __attribute__((ext_vector_type(4))) float f32x4;
typedef __attribute__((ext_vector_type(16))) float f32x16;

#define MFMA_BF16(a, b, c) __builtin_amdgcn_mfma_f32_16x16x32_bf16((a), (b), (c), 0, 0, 0)
#define MFMA32(a, b, c) __builtin_amdgcn_mfma_f32_32x32x16_bf16((a), (b), (c), 0, 0, 0)
#define BAR() __builtin_amdgcn_s_barrier()
#define WAITV(n) asm volatile("s_waitcnt vmcnt(" #n ")" ::: "memory")

#if __has_builtin(__builtin_amdgcn_exp2f)
#define EXP2(x) __builtin_amdgcn_exp2f(x)
#else
#define EXP2(x) exp2f(x)
#endif

__device__ __forceinline__ u16 f2bf(float f) {
    u32 u = __builtin_bit_cast(u32, f);
    u32 r = u + 0x7FFFu + ((u >> 16) & 1u);   // round-to-nearest-even
    return (u16)(r >> 16);
}

__device__ __forceinline__ void gld16(const void* g, void* s) {
    __builtin_amdgcn_global_load_lds(
        (const __attribute__((address_space(1))) unsigned int*)g,
        (__attribute__((address_space(3))) unsigned int*)s, 16, 0, 0);
}

// ---------------- fused f32 -> bf16 convert of all 4 weights ----------------
__global__ __launch_bounds__(256) void cvtall_k(const float* __restrict__ w0,
                                                const float* __restrict__ w1,
                                                const float* __restrict__ w2,
                                                const float* __restrict__ w3,
                                                u16* o0, u16* o1, u16* o2, u16* o3) {
    int j = blockIdx.x * 256 + threadIdx.x;   // quad index
    const float* src; u16* dst;
    if (j < 786432)                       { src = w0; dst = o0; }
    else if ((j -= 786432) < 262144)      { src = w1; dst = o1; }
    else if ((j -= 262144) < 1048576)     { src = w2; dst = o2; }
    else { j -= 1048576;                    src = w3; dst = o3; }
    float4 v = ((const float4*)src)[j];
    ushort4 o;
    o.x = f2bf(v.x); o.y = f2bf(v.y); o.z = f2bf(v.z); o.w = f2bf(v.w);
    ((ushort4*)dst)[j] = o;
}

// ---------------- LayerNorm (1024 cols) -> bf16 ----------------
__global__ __launch_bounds__(256) void ln_k(const float* __restrict__ x,
                                            u16* __restrict__ out,
                                            const float* __restrict__ sc,
                                            const float* __restrict__ bi) {
    const int row = blockIdx.x;
    const int tid = threadIdx.x;
    const float4 v = ((const float4*)(x + (size_t)row * 1024))[tid];
    float s  = v.x + v.y + v.z + v.w;
    float s2 = v.x*v.x + v.y*v.y + v.z*v.z + v.w*v.w;
    #pragma unroll
    for (int m = 32; m; m >>= 1) { s += __shfl_xor(s, m); s2 += __shfl_xor(s2, m); }
    __shared__ float red[8];
    const int w = tid >> 6, l = tid & 63;
    if (l == 0) { red[w] = s; red[4 + w] = s2; }
    __syncthreads();
    s  = red[0] + red[1] + red[2] + red[3];
    s2 = red[4] + red[5] + red[6] + red[7];
    const float mu  = s * (1.0f / 1024.0f);
    const float var = s2 * (1.0f / 1024.0f) - mu * mu;
    const float rs  = rsqrtf(var + 1e-5f);
    const float4 sv = ((const float4*)sc)[tid];
    const float4 bv = ((const float4*)bi)[tid];
    ushort4 o;
    o.x = f2bf((v.x - mu) * rs * sv.x + bv.x);
    o.y = f2bf((v.y - mu) * rs * sv.y + bv.y);
    o.z = f2bf((v.z - mu) * rs * sv.z + bv.z);
    o.w = f2bf((v.w - mu) * rs * sv.w + bv.w);
    ((ushort4*)(out + (size_t)row * 1024))[tid] = o;
}

// ---------------- 256^2-tile GEMM, BK=64, 2-slot, 2 barriers/tile ------------
// 2D-chunked XCD remap (each XCD owns a rect of tiles -> L2-resident panels).
// EPI 0 (qkv): col<1024 scaled by 0.125*log2e; col>=2048 written TRANSPOSED
// to vtout[bh][d][token]. EPI 2: tanh-form gelu -> bf16.
template<int NT, int EPI>
__global__ __launch_bounds__(512, 1) void gemm256_k(const u16* __restrict__ A,
                                                    const u16* __restrict__ B,
                                                    u16* __restrict__ Cb,
                                                    u16* __restrict__ vtout,
                                                    int M, int N, int K) {
    extern __shared__ u16 L[];          // 2 slots x 32768 u16
    const int tid = threadIdx.x;
    const int w = tid >> 6, l = tid & 63, g = l >> 4, lc = l & 15;
    const int wr = w >> 2, wc = w & 3;

    // chunked XCD remap
    const int gx = gridDim.x, gy = gridDim.y;
    const int lin = blockIdx.x + gx * blockIdx.y;
    const int rx = gx >> 2, cy = gy >> 1;
    const int xcd = lin & 7, slot = lin >> 3;
    const int brow = (xcd & 3) * rx + (slot % rx);
    const int bcol = (xcd >> 2) * cy + (slot / rx);
    const int row0 = brow * 256, col0 = bcol * 256;

    const u16* gA = A + (size_t)row0 * K;
    const u16* gB = B + (size_t)col0 * K;
    int srow[4], soct[4];
    #pragma unroll
    for (int p = 0; p < 4; ++p) {
        const int idx = p * 512 + tid;
        srow[p] = idx >> 3;
        soct[p] = (idx & 7) ^ (srow[p] & 7);
    }

#define STG(t, p) do { \
        char* base_ = (char*)L + ((t) & 1) * 65536; \
        gld16(gA + (size_t)srow[p] * K + (size_t)(t) * 64 + soct[p] * 8, \
              base_ + ((p) * 512 + tid) * 16); \
        gld16(gB + (size_t)srow[p] * K + (size_t)(t) * 64 + soct[p] * 8, \
              base_ + 32768 + ((p) * 512 + tid) * 16); \
    } while (0)

    f32x4 acc[8][4] = {};

    STG(0, 0); STG(0, 1); STG(0, 2); STG(0, 3);

    const int ocx = lc & 7;

    for (int t = 0; t < NT; ++t) {
        const bool pf = (t + 1 < NT);
        if (pf) { STG(t + 1, 0); WAITV(2); } else { WAITV(0); }
        BAR();

        const u16* La = L + (t & 1) * 32768;
        const u16* Lb = La + 16384;

        bf16x8 bfr[4][2];
        #pragma unroll
        for (int j = 0; j < 4; ++j)
            #pragma unroll
            for (int kk = 0; kk < 2; ++kk)
                bfr[j][kk] = *(const bf16x8*)
                    &Lb[(wc * 64 + j * 16 + lc) * 64 + (((kk * 4 + g) ^ ocx) * 8)];

        #pragma unroll
        for (int ph = 0; ph < 4; ++ph) {
            if (ph == 2) BAR();         // mid-barrier: bounds straggler lag
            bf16x8 af[2][2];
            #pragma unroll
            for (int ii = 0; ii < 2; ++ii)
                #pragma unroll
                for (int kk = 0; kk < 2; ++kk)
                    af[ii][kk] = *(const bf16x8*)
                        &La[(wr * 128 + (ph * 2 + ii) * 16 + lc) * 64 +
                            (((kk * 4 + g) ^ ocx) * 8)];
            __builtin_amdgcn_s_setprio(1);
            #pragma unroll
            for (int ii = 0; ii < 2; ++ii)
                #pragma unroll
                for (int j = 0; j < 4; ++j)
                    #pragma unroll
                    for (int kk = 0; kk < 2; ++kk)
                        acc[ph * 2 + ii][j] = MFMA_BF16(af[ii][kk], bfr[j][kk],
                                                        acc[ph * 2 + ii][j]);
            __builtin_amdgcn_s_setprio(0);
            if (pf && ph < 3) STG(t + 1, ph + 1);
        }
    }
#undef STG

    #pragma unroll
    for (int i = 0; i < 8; ++i)
        #pragma unroll
        for (int j = 0; j < 4; ++j) {
            const int rowb = row0 + wr * 128 + i * 16 + g * 4;
            const int col  = col0 + wc * 64 + j * 16 + lc;
            if (EPI == 0 && col >= 2048) {
                // V: write transposed to vt[bh][d][token], 4 tokens packed
                u32 lo, hi;
                asm("v_cvt_pk_bf16_f32 %0, %1, %2"
                    : "=v"(lo) : "v"(acc[i][j][0]), "v"(acc[i][j][1]));
                asm("v_cvt_pk_bf16_f32 %0, %1, %2"
                    : "=v"(hi) : "v"(acc[i][j][2]), "v"(acc[i][j][3]));
                const int hd = col - 2048, bb = rowb >> 11, token = rowb & 2047;
                uint2 pk; pk.x = lo; pk.y = hi;
                *(uint2*)(vtout + ((size_t)(bb * 16 + (hd >> 6)) * 64 + (hd & 63)) * 2048
                          + token) = pk;
            } else {
                #pragma unroll
                for (int r = 0; r < 4; ++r) {
                    const size_t off = (size_t)(rowb + r) * N + col;
                    const float v = acc[i][j][r];
                    if (EPI == 0) {
                        const float vv = (col < 1024) ? v * 0.180336880f : v;
                        Cb[off] = f2bf(vv);
                    } else {
                        // tanh-form gelu: x*e/(e+1), e = 2^(2u*log2e)
                        const float u2 = fminf((v + 0.044715f * v * v * v)
                                               * 2.302118131f, 126.0f);
                        const float e = EXP2(u2);
                        Cb[off] = f2bf(v * e / (e + 1.0f));
                    }
                }
            }
        }
}

// ---------------- 128^2-tile, 8-wave, BK=64, 4-slot ring, dist-3 -------------
// All staging POST-top-barrier: STAGE(t+3) overwrites slot (t-1)&3, which was
// fully retired one barrier ago -- unconditionally race-free; 1 barrier/tile.
// Counted drain: steady WAITV(8) (t+1,t+2 in flight), tail 8->4->0.
// 8 waves (4Mx2N), per-wave 32x128 out. Epilogue: Cf = v + resid (f32).
template<int NT>
__global__ __launch_bounds__(512, 1) void gemm128w8_k(const u16* __restrict__ A,
                                                      const u16* __restrict__ B,
                                                      float* __restrict__ Cf,
                                                      const float* __restrict__ resid,
                                                      int M, int N, int K) {
    extern __shared__ u16 L[];          // 4 slots x 16384 u16 (B 8192 | A 8192)
    const int tid = threadIdx.x;
    const int w = tid >> 6, l = tid & 63, g = l >> 4, lc = l & 15;
    const int wr = w >> 1, wc = w & 1;
    const int row0 = blockIdx.x * 128, col0 = blockIdx.y * 128;

    const u16* gA = A + (size_t)row0 * K;
    const u16* gB = B + (size_t)col0 * K;
    const int srow = tid >> 3;
    const int soct = (tid & 7) ^ (srow & 7);

#define STG8(t) do { \
        char* base_ = (char*)L + ((t) & 3) * 32768; \
        _Pragma("unroll") \
        for (int p = 0; p < 4; ++p) { \
            const u16* src_ = (p < 2) ? gB : gA; \
            const int row_ = ((p & 1) << 6) + srow; \
            gld16(src_ + (size_t)row_ * K + (size_t)(t) * 64 + soct * 8, \
                  base_ + p * 8192 + tid * 16); \
        } \
    } while (0)

    f32x4 acc[2][4] = {};

    STG8(0); STG8(1); STG8(2);

    const int ocx = lc & 7;

    for (int t = 0; t < NT; ++t) {
        if      (t + 2 < NT) WAITV(8);
        else if (t + 1 < NT) WAITV(4);
        else                 WAITV(0);
        BAR();
        if (t + 3 < NT) STG8(t + 3);

        const u16* Lb = L + (t & 3) * 16384;
        const u16* La = Lb + 8192;

        bf16x8 bfr[4][2], af[2][2];
        #pragma unroll
        for (int j = 0; j < 4; ++j)
            #pragma unroll
            for (int kk = 0; kk < 2; ++kk)
                bfr[j][kk] = *(const bf16x8*)
                    &Lb[(wc * 64 + j * 16 + lc) * 64 + (((kk * 4 + g) ^ ocx) * 8)];
        #pragma unroll
        for (int ii = 0; ii < 2; ++ii)
            #pragma unroll
            for (int kk = 0; kk < 2; ++kk)
                af[ii][kk] = *(const bf16x8*)
                    &La[(wr * 32 + ii * 16 + lc) * 64 + (((kk * 4 + g) ^ ocx) * 8)];

        __builtin_amdgcn_s_setprio(1);
        #pragma unroll
        for (int ii = 0; ii < 2; ++ii)
            #pragma unroll
            for (int j = 0; j < 4; ++j)
                #pragma unroll
                for (int kk = 0; kk < 2; ++kk)
                    acc[ii][j] = MFMA_BF16(af[ii][kk], bfr[j][kk], acc[ii][j]);
        __builtin_amdgcn_s_setprio(0);
    }
#undef STG8

    #pragma unroll
    for (int i = 0; i < 2; ++i)
        #pragma unroll
        for (int j = 0; j < 4; ++j)
            #pragma unroll
            for (int r = 0; r < 4; ++r) {
                const int row = row0 + wr * 32 + i * 16 + g * 4 + r;
                const int col = col0 + wc * 64 + j * 16 + lc;
                const size_t off = (size_t)row * N + col;
                Cf[off] = acc[i][j][r] + resid[off];
            }
}

// ---------------- Flash attention: B=2, H=16, S=2048, D=64 -------------------
// 32x32x16 MFMA version: 4 waves x 32 q-rows (QBLK=128, 256 thr). Halves DS
// reads/FLOP and MFMA instrs/FLOP vs 16x16. grid (bh, qt) XCD locality;
// K/V 2-slot dbuf, 48 KB LDS -> 3 blocks/CU. Swapped QK^T (C/D: col=lane&31,
// row=(reg&3)+8*(reg>>2)+4*(lane>>5)); A/B: row/col=lane&31, k=(lane>>5)*8+e.
// defer-max softmax (1 shfl per reduce); cvt_pk P-pack; Q pre-scaled upstream.
__global__ __launch_bounds__(256) void attn_k(const u16* __restrict__ qkv,
                                              const u16* __restrict__ vt,
                                              u16* __restrict__ ctx) {
    const int bh = blockIdx.x;          // 0..31  (XCD-locality axis)
    const int qt = blockIdx.y;          // 0..15  (q tile of 128 rows)
    const int b = bh >> 4, h = bh & 15;
    const int tid = threadIdx.x, w = tid >> 6, l = tid & 63;
    const int lo = l & 31, hi = l >> 5;
    const size_t tok0 = (size_t)b * 2048;

    const u16* Qg  = qkv + (tok0 + qt * 128) * 3072 + h * 64;
    const u16* Kg  = qkv + tok0 * 3072 + 1024 + h * 64;
    const u16* Vtg = vt + (size_t)bh * 64 * 2048;      // [d][token-in-batch]

    __shared__ u16 Ks[2][64 * 64];
    __shared__ u16 Vts[2][64 * 64];
    __shared__ u16 QPs[128 * 64];       // Q tile in prologue, then P (32x64/wave)
    u16* Pw = QPs + w * 2048;           // wave-private rows w*32..+31

    // prologue: Q (128x64 = 1024 slots, 4/thread) + K/V tile 0 (2/thread each)
    #pragma unroll
    for (int c = 0; c < 4; ++c) {
        const int idx = c * 256 + tid;
        const int qr = idx >> 3, qc = (idx & 7) ^ (qr & 7);
        gld16(Qg + (size_t)qr * 3072 + qc * 8, (char*)QPs + idx * 16);
    }
    const int s0r = tid >> 3,         s0c = (tid & 7) ^ (s0r & 7);
    const int s1r = (tid + 256) >> 3, s1c = ((tid + 256) & 7) ^ (s1r & 7);
    const u16* kp0 = Kg + (size_t)s0r * 3072 + s0c * 8;
    const u16* kp1 = Kg + (size_t)s1r * 3072 + s1c * 8;
    const u16* vp0 = Vtg + (size_t)s0r * 2048 + s0c * 8;
    const u16* vp1 = Vtg + (size_t)s1r * 2048 + s1c * 8;
    gld16(kp0, (char*)Ks[0] + tid * 16);
    gld16(kp1, (char*)Ks[0] + (tid + 256) * 16);
    gld16(vp0, (char*)Vts[0] + tid * 16);
    gld16(vp1, (char*)Vts[0] + (tid + 256) * 16);
    kp0 += 64 * 3072; kp1 += 64 * 3072; vp0 += 64; vp1 += 64;
    __syncthreads();

    // Q B-frags (k = kk*16 + hi*8 + e), row q = w*32 + lo  (own wave's region)
    bf16x8 qf[4];
    {
        const int qrow = w * 32 + lo;
        #pragma unroll
        for (int kk = 0; kk < 4; ++kk)
            qf[kk] = *(const bf16x8*)
                &QPs[qrow * 64 + (((kk * 2 + hi) ^ (qrow & 7)) * 8)];
    }

    f32x16 oacc[2] = {};                // [db]: d = db*32+lo, q = creg(reg,hi)
    float mrow = -1e30f, lrow = 0.0f;   // per-lane: q = lo
    const int psw = lo & 7;             // P/Q-row swizzle for this lane's q

    for (int kt = 0; kt < 32; ++kt) {
        WAITV(0);                        // tile-kt loads landed (staged last iter)
        BAR();
        if (kt + 1 < 32) {
            char* kd = (char*)Ks[(kt + 1) & 1];
            char* vd = (char*)Vts[(kt + 1) & 1];
            gld16(kp0, kd + tid * 16);
            gld16(kp1, kd + (tid + 256) * 16);
            gld16(vp0, vd + tid * 16);
            gld16(vp1, vd + (tid + 256) * 16);
            kp0 += 64 * 3072; kp1 += 64 * 3072; vp0 += 64; vp1 += 64;
        }
        const u16* Kc = Ks[kt & 1];
        const u16* Vc = Vts[kt & 1];

        // S^T: sacc[kb] holds S[key = kb*32 + creg][q = lo]
        f32x16 sacc[2] = {};
        __builtin_amdgcn_s_setprio(1);
        #pragma unroll
        for (int kb = 0; kb < 2; ++kb) {
            const int krow = kb * 32 + lo;
            #pragma unroll
            for (int kk = 0; kk < 4; ++kk) {
                const bf16x8 kf = *(const bf16x8*)
                    &Kc[krow * 64 + (((kk * 2 + hi) ^ (krow & 7)) * 8)];
                sacc[kb] = MFMA32(kf, qf[kk], sacc[kb]);
            }
        }
        __builtin_amdgcn_s_setprio(0);

        // online softmax (log2 domain), defer-max THR=8, v_max3 over 32 vals
        const float* sv = (const float*)sacc;
        float mx;
        {
            float m = sv[0];
            #pragma unroll
            for (int q = 0; q < 15; ++q) {
                float t;
                asm("v_max3_f32 %0, %1, %2, %3"
                    : "=v"(t) : "v"(m), "v"(sv[2 * q + 1]), "v"(sv[2 * q + 2]));
                m = t;
            }
            mx = fmaxf(m, sv[31]);
        }
        mx = fmaxf(mx, __shfl_xor(mx, 32));
        const bool ru = __any(mx > mrow + 8.0f);
        float corr = 1.0f;
        if (ru) {
            const float mnew = fmaxf(mrow, mx);
            corr = EXP2(mrow - mnew);
            mrow = mnew;
        }

        float p[32];
        float ps = 0.0f;
        #pragma unroll
        for (int i = 0; i < 32; ++i) {
            const float pv = EXP2(sv[i] - mrow);
            p[i] = pv;
            ps += pv;
        }
        ps += __shfl_xor(ps, 32);

        // pack P -> LDS: row q=lo; regs 4j..4j+3 = keys kb*32 + 8j + 4*hi ..+3
        #pragma unroll
        for (int kb = 0; kb < 2; ++kb)
            #pragma unroll
            for (int j = 0; j < 4; ++j) {
                uint2 pk;
                asm("v_cvt_pk_bf16_f32 %0, %1, %2"
                    : "=v"(pk.x) : "v"(p[kb * 16 + 4 * j]), "v"(p[kb * 16 + 4 * j + 1]));
                asm("v_cvt_pk_bf16_f32 %0, %1, %2"
                    : "=v"(pk.y) : "v"(p[kb * 16 + 4 * j + 2]), "v"(p[kb * 16 + 4 * j + 3]));
                *(uint2*)&Pw[lo * 64 + (((kb * 4 + j) ^ psw) * 8) + hi * 4] = pk;
            }

        if (ru) {
            lrow = lrow * corr + ps;
            // rescale O: oacc rows are q' = (reg&3)+8*(reg>>2)+4*hi
            float cq[16];
            #pragma unroll
            for (int r = 0; r < 16; ++r)
                cq[r] = __shfl(corr, (r & 3) + 8 * (r >> 2) + 4 * hi);
            #pragma unroll
            for (int db = 0; db < 2; ++db)
                #pragma unroll
                for (int r = 0; r < 16; ++r) oacc[db][r] *= cq[r];
        } else {
            lrow += ps;
        }

        // O += P @ V  (P A-frag: row q=lo, k=key; V B-frag: col d, k=key)
        __builtin_amdgcn_s_setprio(1);
        #pragma unroll
        for (int kkk = 0; kkk < 4; ++kkk) {
            const bf16x8 pf = *(const bf16x8*)
                &Pw[lo * 64 + (((kkk * 2 + hi) ^ psw) * 8)];
            #pragma unroll
            for (int db = 0; db < 2; ++db) {
                const int drow = db * 32 + lo;
                const bf16x8 vf = *(const bf16x8*)
                    &Vc[drow * 64 + (((kkk * 2 + hi) ^ (drow & 7)) * 8)];
                oacc[db] = MFMA32(pf, vf, oacc[db]);
            }
        }
        __builtin_amdgcn_s_setprio(0);
    }

    // epilogue: normalize (lrow at lane q=lo; broadcast per output row), store
    float lq[16];
    #pragma unroll
    for (int r = 0; r < 16; ++r)
        lq[r] = 1.0f / __shfl(lrow, (r & 3) + 8 * (r >> 2) + 4 * hi);
    #pragma unroll
    for (int db = 0; db < 2; ++db)
        #pragma unroll
        for (int r = 0; r < 16; ++r) {
            const float o = oacc[db][r] * lq[r];
            const int qrow = (r & 3) + 8 * (r >> 2) + 4 * hi;
            const size_t token = tok0 + qt * 128 + w * 32 + qrow;
            ctx[token * 1024 + h * 64 + db * 32 + lo] = f2bf(o);
        }
}

// -----------------------------------------------------------------------------
extern "C" void kernel_launch(void* const* d_in, const int* in_sizes, int n_in,
                              void* d_out, int out_size, void* d_ws, size_t ws_size,
                              hipStream_t stream) {
    const float* x      = (const float*)d_in[0];
    const float* qkv_w  = (const float*)d_in[1];
    const float* out_w  = (const float*)d_in[2];
    const float* up_w   = (const float*)d_in[3];
    const float* down_w = (const float*)d_in[4];
    const float* n1s    = (const float*)d_in[5];
    const float* n1b    = (const float*)d_in[6];
    const float* n2s    = (const float*)d_in[7];
    const float* n2b    = (const float*)d_in[8];
    float* out = (float*)d_out;

    char* ws = (char*)d_ws;
    size_t off = 0;
    auto alloc = [&](size_t bytes) -> void* {
        void* p = ws + off;
        off += (bytes + 255) & ~(size_t)255;
        return p;
    };
    u16*   qkvw_b = (u16*)alloc(3072ull * 1024 * 2);
    u16*   outw_b = (u16*)alloc(1024ull * 1024 * 2);
    u16*   upw_b  = (u16*)alloc(4096ull * 1024 * 2);
    u16*   dnw_b  = (u16*)alloc(1024ull * 4096 * 2);
    u16*   h_b    = (u16*)alloc(4096ull * 1024 * 2);
    u16*   qkv_o  = (u16*)alloc(4096ull * 3072 * 2);
    u16*   ctx    = (u16*)alloc(4096ull * 1024 * 2);
    float* x2     = (float*)alloc(4096ull * 1024 * 4);
    u16*   u      = (u16*)alloc(4096ull * 4096 * 2);
    // vt aliases u: vt live [qkv-gemm .. attn_k]; u live [ffn-up .. ffn-down].
    u16*   vt     = u;

    hipFuncSetAttribute((const void*)&gemm256_k<16, 0>,
                        hipFuncAttributeMaxDynamicSharedMemorySize, 131072);
    hipFuncSetAttribute((const void*)&gemm256_k<16, 2>,
                        hipFuncAttributeMaxDynamicSharedMemorySize, 131072);
    hipFuncSetAttribute((const void*)&gemm128w8_k<16>,
                        hipFuncAttributeMaxDynamicSharedMemorySize, 131072);
    hipFuncSetAttribute((const void*)&gemm128w8_k<64>,
                        hipFuncAttributeMaxDynamicSharedMemorySize, 131072);

    // fused weight conversions (one launch)
    cvtall_k<<<12288, 256, 0, stream>>>(qkv_w, out_w, up_w, down_w,
                                        qkvw_b, outw_b, upw_b, dnw_b);

    // --- attention sublayer ---
    ln_k<<<4096, 256, 0, stream>>>(x, h_b, n1s, n1b);
    gemm256_k<16, 0><<<dim3(16, 12), 512, 131072, stream>>>(h_b, qkvw_b, qkv_o, vt,
                                                            4096, 3072, 1024);
    attn_k<<<dim3(32, 16), 256, 0, stream>>>(qkv_o, vt, ctx);
    // proj: x2 = x + ctx@outw^T (8-wave, 4-slot ring)
    gemm128w8_k<16><<<dim3(32, 8), 512, 131072, stream>>>(ctx, outw_b, x2, x,
                                                          4096, 1024, 1024);

    // --- FFN sublayer ---
    ln_k<<<4096, 256, 0, stream>>>(x2, h_b, n2s, n2b);
    gemm256_k<16, 2><<<dim3(16, 16), 512, 131072, stream>>>(h_b, upw_b, u, nullptr,
                                                            4096, 4096, 1024);
    // down: out = x2 + u@dnw^T (8-wave, 4-slot ring, direct)
    gemm128w8_k<64><<<dim3(32, 8), 512, 131072, stream>>>(u, dnw_b, out, x2,
                                                          4096, 1024, 4096);
}

// Round 19
// 200.776 us; speedup vs baseline: 1.0370x; 1.0370x over previous
//
#include <hip/hip_runtime.h>

typedef unsigned short u16;
typedef unsigned int u32;
typedef __attribute__((ext_vector_type(8))) short bf16x8;
typedef __attribute__((ext_vector_type(4))) float f32x4;

#define MFMA_BF16(a, b, c) __builtin_amdgcn_mfma_f32_16x16x32_bf16((a), (b), (c), 0, 0, 0)
#define BAR() __builtin_amdgcn_s_barrier()
#define WAITV(n) asm volatile("s_waitcnt vmcnt(" #n ")" ::: "memory")

#if __has_builtin(__builtin_amdgcn_exp2f)
#define EXP2(x) __builtin_amdgcn_exp2f(x)
#else
#define EXP2(x) exp2f(x)
#endif

__device__ __forceinline__ u16 f2bf(float f) {
    u32 u = __builtin_bit_cast(u32, f);
    u32 r = u + 0x7FFFu + ((u >> 16) & 1u);   // round-to-nearest-even
    return (u16)(r >> 16);
}

__device__ __forceinline__ void gld16(const void* g, void* s) {
    __builtin_amdgcn_global_load_lds(
        (const __attribute__((address_space(1))) unsigned int*)g,
        (__attribute__((address_space(3))) unsigned int*)s, 16, 0, 0);
}

// ---------------- fused f32 -> bf16 convert of all 4 weights ----------------
__global__ __launch_bounds__(256) void cvtall_k(const float* __restrict__ w0,
                                                const float* __restrict__ w1,
                                                const float* __restrict__ w2,
                                                const float* __restrict__ w3,
                                                u16* o0, u16* o1, u16* o2, u16* o3) {
    int j = blockIdx.x * 256 + threadIdx.x;   // quad index
    const float* src; u16* dst;
    if (j < 786432)                       { src = w0; dst = o0; }
    else if ((j -= 786432) < 262144)      { src = w1; dst = o1; }
    else if ((j -= 262144) < 1048576)     { src = w2; dst = o2; }
    else { j -= 1048576;                    src = w3; dst = o3; }
    float4 v = ((const float4*)src)[j];
    ushort4 o;
    o.x = f2bf(v.x); o.y = f2bf(v.y); o.z = f2bf(v.z); o.w = f2bf(v.w);
    ((ushort4*)dst)[j] = o;
}

// ---------------- LayerNorm (1024 cols) -> bf16 ----------------
__global__ __launch_bounds__(256) void ln_k(const float* __restrict__ x,
                                            u16* __restrict__ out,
                                            const float* __restrict__ sc,
                                            const float* __restrict__ bi) {
    const int row = blockIdx.x;
    const int tid = threadIdx.x;
    const float4 v = ((const float4*)(x + (size_t)row * 1024))[tid];
    float s  = v.x + v.y + v.z + v.w;
    float s2 = v.x*v.x + v.y*v.y + v.z*v.z + v.w*v.w;
    #pragma unroll
    for (int m = 32; m; m >>= 1) { s += __shfl_xor(s, m); s2 += __shfl_xor(s2, m); }
    __shared__ float red[8];
    const int w = tid >> 6, l = tid & 63;
    if (l == 0) { red[w] = s; red[4 + w] = s2; }
    __syncthreads();
    s  = red[0] + red[1] + red[2] + red[3];
    s2 = red[4] + red[5] + red[6] + red[7];
    const float mu  = s * (1.0f / 1024.0f);
    const float var = s2 * (1.0f / 1024.0f) - mu * mu;
    const float rs  = rsqrtf(var + 1e-5f);
    const float4 sv = ((const float4*)sc)[tid];
    const float4 bv = ((const float4*)bi)[tid];
    ushort4 o;
    o.x = f2bf((v.x - mu) * rs * sv.x + bv.x);
    o.y = f2bf((v.y - mu) * rs * sv.y + bv.y);
    o.z = f2bf((v.z - mu) * rs * sv.z + bv.z);
    o.w = f2bf((v.w - mu) * rs * sv.w + bv.w);
    ((ushort4*)(out + (size_t)row * 1024))[tid] = o;
}

// ---------------- 256^2-tile GEMM, BK=64, 2-slot, 2 barriers/tile ------------
// 2D-chunked XCD remap (each XCD owns a rect of tiles -> L2-resident panels).
// EPI 0 (qkv): col<1024 scaled by 0.125*log2e; col>=2048 written TRANSPOSED
// to vtout[bh][d][token]. EPI 2: tanh-form gelu -> bf16.
template<int NT, int EPI>
__global__ __launch_bounds__(512, 1) void gemm256_k(const u16* __restrict__ A,
                                                    const u16* __restrict__ B,
                                                    u16* __restrict__ Cb,
                                                    u16* __restrict__ vtout,
                                                    int M, int N, int K) {
    extern __shared__ u16 L[];          // 2 slots x 32768 u16
    const int tid = threadIdx.x;
    const int w = tid >> 6, l = tid & 63, g = l >> 4, lc = l & 15;
    const int wr = w >> 2, wc = w & 3;

    // chunked XCD remap
    const int gx = gridDim.x, gy = gridDim.y;
    const int lin = blockIdx.x + gx * blockIdx.y;
    const int rx = gx >> 2, cy = gy >> 1;
    const int xcd = lin & 7, slot = lin >> 3;
    const int brow = (xcd & 3) * rx + (slot % rx);
    const int bcol = (xcd >> 2) * cy + (slot / rx);
    const int row0 = brow * 256, col0 = bcol * 256;

    const u16* gA = A + (size_t)row0 * K;
    const u16* gB = B + (size_t)col0 * K;
    int srow[4], soct[4];
    #pragma unroll
    for (int p = 0; p < 4; ++p) {
        const int idx = p * 512 + tid;
        srow[p] = idx >> 3;
        soct[p] = (idx & 7) ^ (srow[p] & 7);
    }

#define STG(t, p) do { \
        char* base_ = (char*)L + ((t) & 1) * 65536; \
        gld16(gA + (size_t)srow[p] * K + (size_t)(t) * 64 + soct[p] * 8, \
              base_ + ((p) * 512 + tid) * 16); \
        gld16(gB + (size_t)srow[p] * K + (size_t)(t) * 64 + soct[p] * 8, \
              base_ + 32768 + ((p) * 512 + tid) * 16); \
    } while (0)

    f32x4 acc[8][4] = {};

    STG(0, 0); STG(0, 1); STG(0, 2); STG(0, 3);

    const int ocx = lc & 7;

    for (int t = 0; t < NT; ++t) {
        const bool pf = (t + 1 < NT);
        if (pf) { STG(t + 1, 0); WAITV(2); } else { WAITV(0); }
        BAR();

        const u16* La = L + (t & 1) * 32768;
        const u16* Lb = La + 16384;

        bf16x8 bfr[4][2];
        #pragma unroll
        for (int j = 0; j < 4; ++j)
            #pragma unroll
            for (int kk = 0; kk < 2; ++kk)
                bfr[j][kk] = *(const bf16x8*)
                    &Lb[(wc * 64 + j * 16 + lc) * 64 + (((kk * 4 + g) ^ ocx) * 8)];

        #pragma unroll
        for (int ph = 0; ph < 4; ++ph) {
            if (ph == 2) BAR();         // mid-barrier: bounds straggler lag
            bf16x8 af[2][2];
            #pragma unroll
            for (int ii = 0; ii < 2; ++ii)
                #pragma unroll
                for (int kk = 0; kk < 2; ++kk)
                    af[ii][kk] = *(const bf16x8*)
                        &La[(wr * 128 + (ph * 2 + ii) * 16 + lc) * 64 +
                            (((kk * 4 + g) ^ ocx) * 8)];
            __builtin_amdgcn_s_setprio(1);
            #pragma unroll
            for (int ii = 0; ii < 2; ++ii)
                #pragma unroll
                for (int j = 0; j < 4; ++j)
                    #pragma unroll
                    for (int kk = 0; kk < 2; ++kk)
                        acc[ph * 2 + ii][j] = MFMA_BF16(af[ii][kk], bfr[j][kk],
                                                        acc[ph * 2 + ii][j]);
            __builtin_amdgcn_s_setprio(0);
            if (pf && ph < 3) STG(t + 1, ph + 1);
        }
    }
#undef STG

    #pragma unroll
    for (int i = 0; i < 8; ++i)
        #pragma unroll
        for (int j = 0; j < 4; ++j) {
            const int rowb = row0 + wr * 128 + i * 16 + g * 4;
            const int col  = col0 + wc * 64 + j * 16 + lc;
            if (EPI == 0 && col >= 2048) {
                // V: write transposed to vt[bh][d][token], 4 tokens packed
                u32 lo, hi;
                asm("v_cvt_pk_bf16_f32 %0, %1, %2"
                    : "=v"(lo) : "v"(acc[i][j][0]), "v"(acc[i][j][1]));
                asm("v_cvt_pk_bf16_f32 %0, %1, %2"
                    : "=v"(hi) : "v"(acc[i][j][2]), "v"(acc[i][j][3]));
                const int hd = col - 2048, bb = rowb >> 11, token = rowb & 2047;
                uint2 pk; pk.x = lo; pk.y = hi;
                *(uint2*)(vtout + ((size_t)(bb * 16 + (hd >> 6)) * 64 + (hd & 63)) * 2048
                          + token) = pk;
            } else {
                #pragma unroll
                for (int r = 0; r < 4; ++r) {
                    const size_t off = (size_t)(rowb + r) * N + col;
                    const float v = acc[i][j][r];
                    if (EPI == 0) {
                        const float vv = (col < 1024) ? v * 0.180336880f : v;
                        Cb[off] = f2bf(vv);
                    } else {
                        // tanh-form gelu: x*e/(e+1), e = 2^(2u*log2e)
                        const float u2 = fminf((v + 0.044715f * v * v * v)
                                               * 2.302118131f, 126.0f);
                        const float e = EXP2(u2);
                        Cb[off] = f2bf(v * e / (e + 1.0f));
                    }
                }
            }
        }
}

// ---------------- 128^2-tile, 8-wave, BK=64, 4-slot ring, dist-3 -------------
// All staging POST-top-barrier: STAGE(t+3) overwrites slot (t-1)&3, which was
// fully retired one barrier ago -- unconditionally race-free; 1 barrier/tile.
// Counted drain: steady WAITV(8) (t+1,t+2 in flight), tail 8->4->0.
// 8 waves (4Mx2N), per-wave 32x128 out. Epilogue: Cf = v + resid (f32).
template<int NT>
__global__ __launch_bounds__(512, 1) void gemm128w8_k(const u16* __restrict__ A,
                                                      const u16* __restrict__ B,
                                                      float* __restrict__ Cf,
                                                      const float* __restrict__ resid,
                                                      int M, int N, int K) {
    extern __shared__ u16 L[];          // 4 slots x 16384 u16 (B 8192 | A 8192)
    const int tid = threadIdx.x;
    const int w = tid >> 6, l = tid & 63, g = l >> 4, lc = l & 15;
    const int wr = w >> 1, wc = w & 1;
    const int row0 = blockIdx.x * 128, col0 = blockIdx.y * 128;

    const u16* gA = A + (size_t)row0 * K;
    const u16* gB = B + (size_t)col0 * K;
    const int srow = tid >> 3;
    const int soct = (tid & 7) ^ (srow & 7);

#define STG8(t) do { \
        char* base_ = (char*)L + ((t) & 3) * 32768; \
        _Pragma("unroll") \
        for (int p = 0; p < 4; ++p) { \
            const u16* src_ = (p < 2) ? gB : gA; \
            const int row_ = ((p & 1) << 6) + srow; \
            gld16(src_ + (size_t)row_ * K + (size_t)(t) * 64 + soct * 8, \
                  base_ + p * 8192 + tid * 16); \
        } \
    } while (0)

    f32x4 acc[2][4] = {};

    STG8(0); STG8(1); STG8(2);

    const int ocx = lc & 7;

    for (int t = 0; t < NT; ++t) {
        if      (t + 2 < NT) WAITV(8);
        else if (t + 1 < NT) WAITV(4);
        else                 WAITV(0);
        BAR();
        if (t + 3 < NT) STG8(t + 3);

        const u16* Lb = L + (t & 3) * 16384;
        const u16* La = Lb + 8192;

        bf16x8 bfr[4][2], af[2][2];
        #pragma unroll
        for (int j = 0; j < 4; ++j)
            #pragma unroll
            for (int kk = 0; kk < 2; ++kk)
                bfr[j][kk] = *(const bf16x8*)
                    &Lb[(wc * 64 + j * 16 + lc) * 64 + (((kk * 4 + g) ^ ocx) * 8)];
        #pragma unroll
        for (int ii = 0; ii < 2; ++ii)
            #pragma unroll
            for (int kk = 0; kk < 2; ++kk)
                af[ii][kk] = *(const bf16x8*)
                    &La[(wr * 32 + ii * 16 + lc) * 64 + (((kk * 4 + g) ^ ocx) * 8)];

        __builtin_amdgcn_s_setprio(1);
        #pragma unroll
        for (int ii = 0; ii < 2; ++ii)
            #pragma unroll
            for (int j = 0; j < 4; ++j)
                #pragma unroll
                for (int kk = 0; kk < 2; ++kk)
                    acc[ii][j] = MFMA_BF16(af[ii][kk], bfr[j][kk], acc[ii][j]);
        __builtin_amdgcn_s_setprio(0);
    }
#undef STG8

    #pragma unroll
    for (int i = 0; i < 2; ++i)
        #pragma unroll
        for (int j = 0; j < 4; ++j)
            #pragma unroll
            for (int r = 0; r < 4; ++r) {
                const int row = row0 + wr * 32 + i * 16 + g * 4 + r;
                const int col = col0 + wc * 64 + j * 16 + lc;
                const size_t off = (size_t)row * N + col;
                Cf[off] = acc[i][j][r] + resid[off];
            }
}

// ---------------- Flash attention: B=2, H=16, S=2048, D=64 -------------------
// R16-best structure: grid (bh, qt) for XCD locality; QBLK=128, 8 waves;
// K/V double-buffered (2-slot), stage(t+1) right after top barrier, WAITV(0);
// 48 KB LDS -> 2 blocks/CU (cross-block overlap hides the serial softmax).
// Swapped QK^T; defer-max softmax; raw v_exp; v_max3; cvt_pk. Q pre-scaled.
__global__ __launch_bounds__(512) void attn_k(const u16* __restrict__ qkv,
                                              const u16* __restrict__ vt,
                                              u16* __restrict__ ctx) {
    const int bh = blockIdx.x;          // 0..31  (XCD-locality axis)
    const int qt = blockIdx.y;          // 0..15  (q tile of 128 rows)
    const int b = bh >> 4, h = bh & 15;
    const int tid = threadIdx.x, w = tid >> 6, l = tid & 63, g = l >> 4, lc = l & 15;
    const size_t tok0 = (size_t)b * 2048;

    const u16* Qg  = qkv + (tok0 + qt * 128) * 3072 + h * 64;
    const u16* Kg  = qkv + tok0 * 3072 + 1024 + h * 64;
    const u16* Vtg = vt + (size_t)bh * 64 * 2048;      // [d][token-in-batch]

    __shared__ u16 Ks[2][64 * 64];
    __shared__ u16 Vts[2][64 * 64];
    __shared__ u16 QPs[128 * 64];       // Q tile in prologue, then P strips
    u16* Pw = QPs + w * 1024;

    // prologue: Q (128x64, 2 slots/thread) + K/V tile 0 (1 slot/thread each)
    {
        const int q0r = tid >> 3,         q0c = (tid & 7) ^ (q0r & 7);
        const int q1r = (tid + 512) >> 3, q1c = ((tid + 512) & 7) ^ (q1r & 7);
        gld16(Qg + (size_t)q0r * 3072 + q0c * 8, (char*)QPs + tid * 16);
        gld16(Qg + (size_t)q1r * 3072 + q1c * 8, (char*)QPs + (tid + 512) * 16);
    }
    const int skr = tid >> 3, skc = (tid & 7) ^ (skr & 7);
    const u16* kp = Kg + (size_t)skr * 3072 + skc * 8;
    const u16* vp = Vtg + (size_t)skr * 2048 + skc * 8;
    gld16(kp, (char*)Ks[0] + tid * 16);
    gld16(vp, (char*)Vts[0] + tid * 16);
    kp += 64 * 3072; vp += 64;
    __syncthreads();

    bf16x8 qf[2];
    {
        const int qrow = w * 16 + lc;
        qf[0] = *(const bf16x8*)&QPs[qrow * 64 + ((g       ^ (lc & 7)) * 8)];
        qf[1] = *(const bf16x8*)&QPs[qrow * 64 + (((4 + g) ^ (lc & 7)) * 8)];
    }

    f32x4 oacc[4] = {};
    float mrow = -1e30f, lrow = 0.0f;   // per-lane: q = lc
    const int hsw = (lc & 7) << 3;      // P row swizzle (u16 units)

    for (int kt = 0; kt < 32; ++kt) {
        WAITV(0);                        // tile-kt loads landed (staged last iter)
        BAR();
        if (kt + 1 < 32) {
            gld16(kp, (char*)Ks[(kt + 1) & 1] + tid * 16);
            gld16(vp, (char*)Vts[(kt + 1) & 1] + tid * 16);
            kp += 64 * 3072; vp += 64;
        }
        const u16* Kc = Ks[kt & 1];
        const u16* Vc = Vts[kt & 1];

        // S^T strip: sacc[nt] holds S[key = nt*16+g*4+r][q = lc]
        f32x4 sacc[4] = {};
        __builtin_amdgcn_s_setprio(1);
        #pragma unroll
        for (int kk = 0; kk < 2; ++kk)
            #pragma unroll
            for (int nt = 0; nt < 4; ++nt) {
                const int krow = nt * 16 + lc;
                const bf16x8 kb = *(const bf16x8*)
                    &Kc[krow * 64 + (((kk * 4 + g) ^ (lc & 7)) * 8)];
                sacc[nt] = MFMA_BF16(kb, qf[kk], sacc[nt]);
            }
        __builtin_amdgcn_s_setprio(0);

        // online softmax (log2 domain) with defer-max, THR=8; v_max3 chain
        float mx;
        {
            const float* sv = (const float*)sacc;
            float m = sv[0];
            #pragma unroll
            for (int q = 0; q < 7; ++q) {
                float t;
                asm("v_max3_f32 %0, %1, %2, %3"
                    : "=v"(t) : "v"(m), "v"(sv[2 * q + 1]), "v"(sv[2 * q + 2]));
                m = t;
            }
            mx = fmaxf(m, sv[15]);
        }
        mx = fmaxf(mx, __shfl_xor(mx, 16));
        mx = fmaxf(mx, __shfl_xor(mx, 32));
        const bool ru = __any(mx > mrow + 8.0f);
        float corr = 1.0f;
        if (ru) {
            const float mnew = fmaxf(mrow, mx);
            corr = EXP2(mrow - mnew);
            mrow = mnew;
        }

        float p[4][4];
        float ps = 0.0f;
        #pragma unroll
        for (int nt = 0; nt < 4; ++nt)
            #pragma unroll
            for (int r = 0; r < 4; ++r) {
                const float pv = EXP2(sacc[nt][r] - mrow);
                p[nt][r] = pv;
                ps += pv;
            }
        ps += __shfl_xor(ps, 16);
        ps += __shfl_xor(ps, 32);

        // pack P -> LDS (b64, swizzled)
        #pragma unroll
        for (int nt = 0; nt < 4; ++nt) {
            uint2 pk;
            asm("v_cvt_pk_bf16_f32 %0, %1, %2" : "=v"(pk.x) : "v"(p[nt][0]), "v"(p[nt][1]));
            asm("v_cvt_pk_bf16_f32 %0, %1, %2" : "=v"(pk.y) : "v"(p[nt][2]), "v"(p[nt][3]));
            *(uint2*)&Pw[lc * 64 + ((nt * 16 + g * 4) ^ hsw)] = pk;
        }

        if (ru) {
            lrow = lrow * corr + ps;
            float cq[4];
            #pragma unroll
            for (int r = 0; r < 4; ++r) cq[r] = __shfl(corr, g * 4 + r);
            #pragma unroll
            for (int nt = 0; nt < 4; ++nt)
                #pragma unroll
                for (int r = 0; r < 4; ++r) oacc[nt][r] *= cq[r];
        } else {
            lrow += ps;
        }

        // O += P @ V
        __builtin_amdgcn_s_setprio(1);
        #pragma unroll
        for (int kk = 0; kk < 2; ++kk) {
            const bf16x8 pa = *(const bf16x8*)
                &Pw[lc * 64 + ((kk * 32 + g * 8) ^ hsw)];
            #pragma unroll
            for (int nt = 0; nt < 4; ++nt) {
                const int vrow = nt * 16 + lc;          // = d
                const bf16x8 vb = *(const bf16x8*)
                    &Vc[vrow * 64 + (((kk * 4 + g) ^ (lc & 7)) * 8)];
                oacc[nt] = MFMA_BF16(pa, vb, oacc[nt]);
            }
        }
        __builtin_amdgcn_s_setprio(0);
    }

    // epilogue: normalize (lrow lives at lane q; broadcast), store
    float lq[4];
    #pragma unroll
    for (int r = 0; r < 4; ++r) lq[r] = 1.0f / __shfl(lrow, g * 4 + r);
    #pragma unroll
    for (int nt = 0; nt < 4; ++nt)
        #pragma unroll
        for (int r = 0; r < 4; ++r) {
            const float o = oacc[nt][r] * lq[r];
            const size_t token = tok0 + qt * 128 + w * 16 + g * 4 + r;
            ctx[token * 1024 + h * 64 + nt * 16 + lc] = f2bf(o);
        }
}

// -----------------------------------------------------------------------------
extern "C" void kernel_launch(void* const* d_in, const int* in_sizes, int n_in,
                              void* d_out, int out_size, void* d_ws, size_t ws_size,
                              hipStream_t stream) {
    const float* x      = (const float*)d_in[0];
    const float* qkv_w  = (const float*)d_in[1];
    const float* out_w  = (const float*)d_in[2];
    const float* up_w   = (const float*)d_in[3];
    const float* down_w = (const float*)d_in[4];
    const float* n1s    = (const float*)d_in[5];
    const float* n1b    = (const float*)d_in[6];
    const float* n2s    = (const float*)d_in[7];
    const float* n2b    = (const float*)d_in[8];
    float* out = (float*)d_out;

    char* ws = (char*)d_ws;
    size_t off = 0;
    auto alloc = [&](size_t bytes) -> void* {
        void* p = ws + off;
        off += (bytes + 255) & ~(size_t)255;
        return p;
    };
    u16*   qkvw_b = (u16*)alloc(3072ull * 1024 * 2);
    u16*   outw_b = (u16*)alloc(1024ull * 1024 * 2);
    u16*   upw_b  = (u16*)alloc(4096ull * 1024 * 2);
    u16*   dnw_b  = (u16*)alloc(1024ull * 4096 * 2);
    u16*   h_b    = (u16*)alloc(4096ull * 1024 * 2);
    u16*   qkv_o  = (u16*)alloc(4096ull * 3072 * 2);
    u16*   ctx    = (u16*)alloc(4096ull * 1024 * 2);
    float* x2     = (float*)alloc(4096ull * 1024 * 4);
    u16*   u      = (u16*)alloc(4096ull * 4096 * 2);
    // vt aliases u: vt live [qkv-gemm .. attn_k]; u live [ffn-up .. ffn-down].
    u16*   vt     = u;

    hipFuncSetAttribute((const void*)&gemm256_k<16, 0>,
                        hipFuncAttributeMaxDynamicSharedMemorySize, 131072);
    hipFuncSetAttribute((const void*)&gemm256_k<16, 2>,
                        hipFuncAttributeMaxDynamicSharedMemorySize, 131072);
    hipFuncSetAttribute((const void*)&gemm128w8_k<16>,
                        hipFuncAttributeMaxDynamicSharedMemorySize, 131072);
    hipFuncSetAttribute((const void*)&gemm128w8_k<64>,
                        hipFuncAttributeMaxDynamicSharedMemorySize, 131072);

    // fused weight conversions (one launch)
    cvtall_k<<<12288, 256, 0, stream>>>(qkv_w, out_w, up_w, down_w,
                                        qkvw_b, outw_b, upw_b, dnw_b);

    // --- attention sublayer ---
    ln_k<<<4096, 256, 0, stream>>>(x, h_b, n1s, n1b);
    gemm256_k<16, 0><<<dim3(16, 12), 512, 131072, stream>>>(h_b, qkvw_b, qkv_o, vt,
                                                            4096, 3072, 1024);
    attn_k<<<dim3(32, 16), 512, 0, stream>>>(qkv_o, vt, ctx);
    // proj: x2 = x + ctx@outw^T (8-wave, 4-slot ring)
    gemm128w8_k<16><<<dim3(32, 8), 512, 131072, stream>>>(ctx, outw_b, x2, x,
                                                          4096, 1024, 1024);

    // --- FFN sublayer ---
    ln_k<<<4096, 256, 0, stream>>>(x2, h_b, n2s, n2b);
    gemm256_k<16, 2><<<dim3(16, 16), 512, 131072, stream>>>(h_b, upw_b, u, nullptr,
                                                            4096, 4096, 1024);
    // down: out = x2 + u@dnw^T (8-wave, 4-slot ring, direct)
    gemm128w8_k<64><<<dim3(32, 8), 512, 131072, stream>>>(u, dnw_b, out, x2,
                                                          4096, 1024, 4096);
}

// Round 20
// 199.747 us; speedup vs baseline: 1.0423x; 1.0052x over previous
//
#include <hip/hip_runtime.h>

typedef unsigned short u16;
typedef unsigned int u32;
typedef __attribute__((ext_vector_type(8))) short bf16x8;
typedef __attribute__((ext_vector_type(4))) float f32x4;

#define MFMA_BF16(a, b, c) __builtin_amdgcn_mfma_f32_16x16x32_bf16((a), (b), (c), 0, 0, 0)
#define BAR() __builtin_amdgcn_s_barrier()
#define WAITV(n) asm volatile("s_waitcnt vmcnt(" #n ")" ::: "memory")

#if __has_builtin(__builtin_amdgcn_exp2f)
#define EXP2(x) __builtin_amdgcn_exp2f(x)
#else
#define EXP2(x) exp2f(x)
#endif

__device__ __forceinline__ u16 f2bf(float f) {
    u32 u = __builtin_bit_cast(u32, f);
    u32 r = u + 0x7FFFu + ((u >> 16) & 1u);   // round-to-nearest-even
    return (u16)(r >> 16);
}

__device__ __forceinline__ void gld16(const void* g, void* s) {
    __builtin_amdgcn_global_load_lds(
        (const __attribute__((address_space(1))) unsigned int*)g,
        (__attribute__((address_space(3))) unsigned int*)s, 16, 0, 0);
}

// ---------------- LayerNorm body (1024 cols) -> bf16 ----------------
__device__ __forceinline__ void ln_body(const float* __restrict__ x, int row,
                                        u16* __restrict__ out,
                                        const float* __restrict__ sc,
                                        const float* __restrict__ bi, int tid) {
    const float4 v = ((const float4*)(x + (size_t)row * 1024))[tid];
    float s  = v.x + v.y + v.z + v.w;
    float s2 = v.x*v.x + v.y*v.y + v.z*v.z + v.w*v.w;
    #pragma unroll
    for (int m = 32; m; m >>= 1) { s += __shfl_xor(s, m); s2 += __shfl_xor(s2, m); }
    __shared__ float red[8];
    const int w = tid >> 6, l = tid & 63;
    if (l == 0) { red[w] = s; red[4 + w] = s2; }
    __syncthreads();
    s  = red[0] + red[1] + red[2] + red[3];
    s2 = red[4] + red[5] + red[6] + red[7];
    const float mu  = s * (1.0f / 1024.0f);
    const float var = s2 * (1.0f / 1024.0f) - mu * mu;
    const float rs  = rsqrtf(var + 1e-5f);
    const float4 sv = ((const float4*)sc)[tid];
    const float4 bv = ((const float4*)bi)[tid];
    ushort4 o;
    o.x = f2bf((v.x - mu) * rs * sv.x + bv.x);
    o.y = f2bf((v.y - mu) * rs * sv.y + bv.y);
    o.z = f2bf((v.z - mu) * rs * sv.z + bv.z);
    o.w = f2bf((v.w - mu) * rs * sv.w + bv.w);
    ((ushort4*)(out + (size_t)row * 1024))[tid] = o;
}

// ---------------- standalone LayerNorm (for ln2) ----------------
__global__ __launch_bounds__(256) void ln_k(const float* __restrict__ x,
                                            u16* __restrict__ out,
                                            const float* __restrict__ sc,
                                            const float* __restrict__ bi) {
    ln_body(x, blockIdx.x, out, sc, bi, threadIdx.x);
}

// ------- fused: weight converts (blocks 0..12287) + LN1 (blocks 12288+) ------
__global__ __launch_bounds__(256) void cvtln_k(const float* __restrict__ w0,
                                               const float* __restrict__ w1,
                                               const float* __restrict__ w2,
                                               const float* __restrict__ w3,
                                               u16* o0, u16* o1, u16* o2, u16* o3,
                                               const float* __restrict__ x,
                                               u16* __restrict__ h,
                                               const float* __restrict__ n1s,
                                               const float* __restrict__ n1b) {
    if (blockIdx.x >= 12288) {
        ln_body(x, blockIdx.x - 12288, h, n1s, n1b, threadIdx.x);
        return;
    }
    int j = blockIdx.x * 256 + threadIdx.x;   // quad index
    const float* src; u16* dst;
    if (j < 786432)                       { src = w0; dst = o0; }
    else if ((j -= 786432) < 262144)      { src = w1; dst = o1; }
    else if ((j -= 262144) < 1048576)     { src = w2; dst = o2; }
    else { j -= 1048576;                    src = w3; dst = o3; }
    float4 v = ((const float4*)src)[j];
    ushort4 o;
    o.x = f2bf(v.x); o.y = f2bf(v.y); o.z = f2bf(v.z); o.w = f2bf(v.w);
    ((ushort4*)dst)[j] = o;
}

// ---------------- 256^2-tile GEMM, BK=64, 2-slot, 2 barriers/tile ------------
// 2D-chunked XCD remap (each XCD owns a rect of tiles -> L2-resident panels).
// EPI 0 (qkv): col<1024 scaled by 0.125*log2e; col>=2048 written TRANSPOSED
// to vtout[bh][d][token]. EPI 2: tanh-form gelu -> bf16.
template<int NT, int EPI>
__global__ __launch_bounds__(512, 1) void gemm256_k(const u16* __restrict__ A,
                                                    const u16* __restrict__ B,
                                                    u16* __restrict__ Cb,
                                                    u16* __restrict__ vtout,
                                                    int M, int N, int K) {
    extern __shared__ u16 L[];          // 2 slots x 32768 u16
    const int tid = threadIdx.x;
    const int w = tid >> 6, l = tid & 63, g = l >> 4, lc = l & 15;
    const int wr = w >> 2, wc = w & 3;

    // chunked XCD remap
    const int gx = gridDim.x, gy = gridDim.y;
    const int lin = blockIdx.x + gx * blockIdx.y;
    const int rx = gx >> 2, cy = gy >> 1;
    const int xcd = lin & 7, slot = lin >> 3;
    const int brow = (xcd & 3) * rx + (slot % rx);
    const int bcol = (xcd >> 2) * cy + (slot / rx);
    const int row0 = brow * 256, col0 = bcol * 256;

    const u16* gA = A + (size_t)row0 * K;
    const u16* gB = B + (size_t)col0 * K;
    int srow[4], soct[4];
    #pragma unroll
    for (int p = 0; p < 4; ++p) {
        const int idx = p * 512 + tid;
        srow[p] = idx >> 3;
        soct[p] = (idx & 7) ^ (srow[p] & 7);
    }

#define STG(t, p) do { \
        char* base_ = (char*)L + ((t) & 1) * 65536; \
        gld16(gA + (size_t)srow[p] * K + (size_t)(t) * 64 + soct[p] * 8, \
              base_ + ((p) * 512 + tid) * 16); \
        gld16(gB + (size_t)srow[p] * K + (size_t)(t) * 64 + soct[p] * 8, \
              base_ + 32768 + ((p) * 512 + tid) * 16); \
    } while (0)

    f32x4 acc[8][4] = {};

    STG(0, 0); STG(0, 1); STG(0, 2); STG(0, 3);

    const int ocx = lc & 7;

    for (int t = 0; t < NT; ++t) {
        const bool pf = (t + 1 < NT);
        if (pf) { STG(t + 1, 0); WAITV(2); } else { WAITV(0); }
        BAR();

        const u16* La = L + (t & 1) * 32768;
        const u16* Lb = La + 16384;

        bf16x8 bfr[4][2];
        #pragma unroll
        for (int j = 0; j < 4; ++j)
            #pragma unroll
            for (int kk = 0; kk < 2; ++kk)
                bfr[j][kk] = *(const bf16x8*)
                    &Lb[(wc * 64 + j * 16 + lc) * 64 + (((kk * 4 + g) ^ ocx) * 8)];

        #pragma unroll
        for (int ph = 0; ph < 4; ++ph) {
            if (ph == 2) BAR();         // mid-barrier: bounds straggler lag
            bf16x8 af[2][2];
            #pragma unroll
            for (int ii = 0; ii < 2; ++ii)
                #pragma unroll
                for (int kk = 0; kk < 2; ++kk)
                    af[ii][kk] = *(const bf16x8*)
                        &La[(wr * 128 + (ph * 2 + ii) * 16 + lc) * 64 +
                            (((kk * 4 + g) ^ ocx) * 8)];
            __builtin_amdgcn_s_setprio(1);
            #pragma unroll
            for (int ii = 0; ii < 2; ++ii)
                #pragma unroll
                for (int j = 0; j < 4; ++j)
                    #pragma unroll
                    for (int kk = 0; kk < 2; ++kk)
                        acc[ph * 2 + ii][j] = MFMA_BF16(af[ii][kk], bfr[j][kk],
                                                        acc[ph * 2 + ii][j]);
            __builtin_amdgcn_s_setprio(0);
            if (pf && ph < 3) STG(t + 1, ph + 1);
        }
    }
#undef STG

    #pragma unroll
    for (int i = 0; i < 8; ++i)
        #pragma unroll
        for (int j = 0; j < 4; ++j) {
            const int rowb = row0 + wr * 128 + i * 16 + g * 4;
            const int col  = col0 + wc * 64 + j * 16 + lc;
            if (EPI == 0 && col >= 2048) {
                // V: write transposed to vt[bh][d][token], 4 tokens packed
                u32 lo, hi;
                asm("v_cvt_pk_bf16_f32 %0, %1, %2"
                    : "=v"(lo) : "v"(acc[i][j][0]), "v"(acc[i][j][1]));
                asm("v_cvt_pk_bf16_f32 %0, %1, %2"
                    : "=v"(hi) : "v"(acc[i][j][2]), "v"(acc[i][j][3]));
                const int hd = col - 2048, bb = rowb >> 11, token = rowb & 2047;
                uint2 pk; pk.x = lo; pk.y = hi;
                *(uint2*)(vtout + ((size_t)(bb * 16 + (hd >> 6)) * 64 + (hd & 63)) * 2048
                          + token) = pk;
            } else {
                #pragma unroll
                for (int r = 0; r < 4; ++r) {
                    const size_t off = (size_t)(rowb + r) * N + col;
                    const float v = acc[i][j][r];
                    if (EPI == 0) {
                        const float vv = (col < 1024) ? v * 0.180336880f : v;
                        Cb[off] = f2bf(vv);
                    } else {
                        // tanh-form gelu: x*e/(e+1), e = 2^(2u*log2e)
                        const float u2 = fminf((v + 0.044715f * v * v * v)
                                               * 2.302118131f, 126.0f);
                        const float e = EXP2(u2);
                        Cb[off] = f2bf(v * e / (e + 1.0f));
                    }
                }
            }
        }
}

// ---------------- 128^2-tile, 8-wave, BK=64, 4-slot ring, dist-3 -------------
// All staging POST-top-barrier: STAGE(t+3) overwrites slot (t-1)&3, which was
// fully retired one barrier ago -- unconditionally race-free; 1 barrier/tile.
// Counted drain: steady WAITV(8) (t+1,t+2 in flight), tail 8->4->0.
// 8 waves (4Mx2N), per-wave 32x128 out. Epilogue: Cf = v + resid (f32).
template<int NT>
__global__ __launch_bounds__(512, 1) void gemm128w8_k(const u16* __restrict__ A,
                                                      const u16* __restrict__ B,
                                                      float* __restrict__ Cf,
                                                      const float* __restrict__ resid,
                                                      int M, int N, int K) {
    extern __shared__ u16 L[];          // 4 slots x 16384 u16 (B 8192 | A 8192)
    const int tid = threadIdx.x;
    const int w = tid >> 6, l = tid & 63, g = l >> 4, lc = l & 15;
    const int wr = w >> 1, wc = w & 1;
    const int row0 = blockIdx.x * 128, col0 = blockIdx.y * 128;

    const u16* gA = A + (size_t)row0 * K;
    const u16* gB = B + (size_t)col0 * K;
    const int srow = tid >> 3;
    const int soct = (tid & 7) ^ (srow & 7);

#define STG8(t) do { \
        char* base_ = (char*)L + ((t) & 3) * 32768; \
        _Pragma("unroll") \
        for (int p = 0; p < 4; ++p) { \
            const u16* src_ = (p < 2) ? gB : gA; \
            const int row_ = ((p & 1) << 6) + srow; \
            gld16(src_ + (size_t)row_ * K + (size_t)(t) * 64 + soct * 8, \
                  base_ + p * 8192 + tid * 16); \
        } \
    } while (0)

    f32x4 acc[2][4] = {};

    STG8(0); STG8(1); STG8(2);

    const int ocx = lc & 7;

    for (int t = 0; t < NT; ++t) {
        if      (t + 2 < NT) WAITV(8);
        else if (t + 1 < NT) WAITV(4);
        else                 WAITV(0);
        BAR();
        if (t + 3 < NT) STG8(t + 3);

        const u16* Lb = L + (t & 3) * 16384;
        const u16* La = Lb + 8192;

        bf16x8 bfr[4][2], af[2][2];
        #pragma unroll
        for (int j = 0; j < 4; ++j)
            #pragma unroll
            for (int kk = 0; kk < 2; ++kk)
                bfr[j][kk] = *(const bf16x8*)
                    &Lb[(wc * 64 + j * 16 + lc) * 64 + (((kk * 4 + g) ^ ocx) * 8)];
        #pragma unroll
        for (int ii = 0; ii < 2; ++ii)
            #pragma unroll
            for (int kk = 0; kk < 2; ++kk)
                af[ii][kk] = *(const bf16x8*)
                    &La[(wr * 32 + ii * 16 + lc) * 64 + (((kk * 4 + g) ^ ocx) * 8)];

        __builtin_amdgcn_s_setprio(1);
        #pragma unroll
        for (int ii = 0; ii < 2; ++ii)
            #pragma unroll
            for (int j = 0; j < 4; ++j)
                #pragma unroll
                for (int kk = 0; kk < 2; ++kk)
                    acc[ii][j] = MFMA_BF16(af[ii][kk], bfr[j][kk], acc[ii][j]);
        __builtin_amdgcn_s_setprio(0);
    }
#undef STG8

    #pragma unroll
    for (int i = 0; i < 2; ++i)
        #pragma unroll
        for (int j = 0; j < 4; ++j)
            #pragma unroll
            for (int r = 0; r < 4; ++r) {
                const int row = row0 + wr * 32 + i * 16 + g * 4 + r;
                const int col = col0 + wc * 64 + j * 16 + lc;
                const size_t off = (size_t)row * N + col;
                Cf[off] = acc[i][j][r] + resid[off];
            }
}

// ---------------- Flash attention: B=2, H=16, S=2048, D=64 -------------------
// R16-best structure: grid (bh, qt) for XCD locality; QBLK=128, 8 waves;
// K/V double-buffered (2-slot), stage(t+1) right after top barrier, WAITV(0);
// 48 KB LDS -> 2 blocks/CU (cross-block overlap hides the serial softmax).
// Swapped QK^T; defer-max softmax; raw v_exp; v_max3; cvt_pk. Q pre-scaled.
__global__ __launch_bounds__(512) void attn_k(const u16* __restrict__ qkv,
                                              const u16* __restrict__ vt,
                                              u16* __restrict__ ctx) {
    const int bh = blockIdx.x;          // 0..31  (XCD-locality axis)
    const int qt = blockIdx.y;          // 0..15  (q tile of 128 rows)
    const int b = bh >> 4, h = bh & 15;
    const int tid = threadIdx.x, w = tid >> 6, l = tid & 63, g = l >> 4, lc = l & 15;
    const size_t tok0 = (size_t)b * 2048;

    const u16* Qg  = qkv + (tok0 + qt * 128) * 3072 + h * 64;
    const u16* Kg  = qkv + tok0 * 3072 + 1024 + h * 64;
    const u16* Vtg = vt + (size_t)bh * 64 * 2048;      // [d][token-in-batch]

    __shared__ u16 Ks[2][64 * 64];
    __shared__ u16 Vts[2][64 * 64];
    __shared__ u16 QPs[128 * 64];       // Q tile in prologue, then P strips
    u16* Pw = QPs + w * 1024;

    // prologue: Q (128x64, 2 slots/thread) + K/V tile 0 (1 slot/thread each)
    {
        const int q0r = tid >> 3,         q0c = (tid & 7) ^ (q0r & 7);
        const int q1r = (tid + 512) >> 3, q1c = ((tid + 512) & 7) ^ (q1r & 7);
        gld16(Qg + (size_t)q0r * 3072 + q0c * 8, (char*)QPs + tid * 16);
        gld16(Qg + (size_t)q1r * 3072 + q1c * 8, (char*)QPs + (tid + 512) * 16);
    }
    const int skr = tid >> 3, skc = (tid & 7) ^ (skr & 7);
    const u16* kp = Kg + (size_t)skr * 3072 + skc * 8;
    const u16* vp = Vtg + (size_t)skr * 2048 + skc * 8;
    gld16(kp, (char*)Ks[0] + tid * 16);
    gld16(vp, (char*)Vts[0] + tid * 16);
    kp += 64 * 3072; vp += 64;
    __syncthreads();

    bf16x8 qf[2];
    {
        const int qrow = w * 16 + lc;
        qf[0] = *(const bf16x8*)&QPs[qrow * 64 + ((g       ^ (lc & 7)) * 8)];
        qf[1] = *(const bf16x8*)&QPs[qrow * 64 + (((4 + g) ^ (lc & 7)) * 8)];
    }

    f32x4 oacc[4] = {};
    float mrow = -1e30f, lrow = 0.0f;   // per-lane: q = lc
    const int hsw = (lc & 7) << 3;      // P row swizzle (u16 units)

    for (int kt = 0; kt < 32; ++kt) {
        WAITV(0);                        // tile-kt loads landed (staged last iter)
        BAR();
        if (kt + 1 < 32) {
            gld16(kp, (char*)Ks[(kt + 1) & 1] + tid * 16);
            gld16(vp, (char*)Vts[(kt + 1) & 1] + tid * 16);
            kp += 64 * 3072; vp += 64;
        }
        const u16* Kc = Ks[kt & 1];
        const u16* Vc = Vts[kt & 1];

        // S^T strip: sacc[nt] holds S[key = nt*16+g*4+r][q = lc]
        f32x4 sacc[4] = {};
        __builtin_amdgcn_s_setprio(1);
        #pragma unroll
        for (int kk = 0; kk < 2; ++kk)
            #pragma unroll
            for (int nt = 0; nt < 4; ++nt) {
                const int krow = nt * 16 + lc;
                const bf16x8 kb = *(const bf16x8*)
                    &Kc[krow * 64 + (((kk * 4 + g) ^ (lc & 7)) * 8)];
                sacc[nt] = MFMA_BF16(kb, qf[kk], sacc[nt]);
            }
        __builtin_amdgcn_s_setprio(0);

        // online softmax (log2 domain) with defer-max, THR=8; v_max3 chain
        float mx;
        {
            const float* sv = (const float*)sacc;
            float m = sv[0];
            #pragma unroll
            for (int q = 0; q < 7; ++q) {
                float t;
                asm("v_max3_f32 %0, %1, %2, %3"
                    : "=v"(t) : "v"(m), "v"(sv[2 * q + 1]), "v"(sv[2 * q + 2]));
                m = t;
            }
            mx = fmaxf(m, sv[15]);
        }
        mx = fmaxf(mx, __shfl_xor(mx, 16));
        mx = fmaxf(mx, __shfl_xor(mx, 32));
        const bool ru = __any(mx > mrow + 8.0f);
        float corr = 1.0f;
        if (ru) {
            const float mnew = fmaxf(mrow, mx);
            corr = EXP2(mrow - mnew);
            mrow = mnew;
        }

        float p[4][4];
        float ps = 0.0f;
        #pragma unroll
        for (int nt = 0; nt < 4; ++nt)
            #pragma unroll
            for (int r = 0; r < 4; ++r) {
                const float pv = EXP2(sacc[nt][r] - mrow);
                p[nt][r] = pv;
                ps += pv;
            }
        ps += __shfl_xor(ps, 16);
        ps += __shfl_xor(ps, 32);

        // pack P -> LDS (b64, swizzled)
        #pragma unroll
        for (int nt = 0; nt < 4; ++nt) {
            uint2 pk;
            asm("v_cvt_pk_bf16_f32 %0, %1, %2" : "=v"(pk.x) : "v"(p[nt][0]), "v"(p[nt][1]));
            asm("v_cvt_pk_bf16_f32 %0, %1, %2" : "=v"(pk.y) : "v"(p[nt][2]), "v"(p[nt][3]));
            *(uint2*)&Pw[lc * 64 + ((nt * 16 + g * 4) ^ hsw)] = pk;
        }

        if (ru) {
            lrow = lrow * corr + ps;
            float cq[4];
            #pragma unroll
            for (int r = 0; r < 4; ++r) cq[r] = __shfl(corr, g * 4 + r);
            #pragma unroll
            for (int nt = 0; nt < 4; ++nt)
                #pragma unroll
                for (int r = 0; r < 4; ++r) oacc[nt][r] *= cq[r];
        } else {
            lrow += ps;
        }

        // O += P @ V
        __builtin_amdgcn_s_setprio(1);
        #pragma unroll
        for (int kk = 0; kk < 2; ++kk) {
            const bf16x8 pa = *(const bf16x8*)
                &Pw[lc * 64 + ((kk * 32 + g * 8) ^ hsw)];
            #pragma unroll
            for (int nt = 0; nt < 4; ++nt) {
                const int vrow = nt * 16 + lc;          // = d
                const bf16x8 vb = *(const bf16x8*)
                    &Vc[vrow * 64 + (((kk * 4 + g) ^ (lc & 7)) * 8)];
                oacc[nt] = MFMA_BF16(pa, vb, oacc[nt]);
            }
        }
        __builtin_amdgcn_s_setprio(0);
    }

    // epilogue: normalize (lrow lives at lane q; broadcast), store
    float lq[4];
    #pragma unroll
    for (int r = 0; r < 4; ++r) lq[r] = 1.0f / __shfl(lrow, g * 4 + r);
    #pragma unroll
    for (int nt = 0; nt < 4; ++nt)
        #pragma unroll
        for (int r = 0; r < 4; ++r) {
            const float o = oacc[nt][r] * lq[r];
            const size_t token = tok0 + qt * 128 + w * 16 + g * 4 + r;
            ctx[token * 1024 + h * 64 + nt * 16 + lc] = f2bf(o);
        }
}

// -----------------------------------------------------------------------------
extern "C" void kernel_launch(void* const* d_in, const int* in_sizes, int n_in,
                              void* d_out, int out_size, void* d_ws, size_t ws_size,
                              hipStream_t stream) {
    const float* x      = (const float*)d_in[0];
    const float* qkv_w  = (const float*)d_in[1];
    const float* out_w  = (const float*)d_in[2];
    const float* up_w   = (const float*)d_in[3];
    const float* down_w = (const float*)d_in[4];
    const float* n1s    = (const float*)d_in[5];
    const float* n1b    = (const float*)d_in[6];
    const float* n2s    = (const float*)d_in[7];
    const float* n2b    = (const float*)d_in[8];
    float* out = (float*)d_out;

    char* ws = (char*)d_ws;
    size_t off = 0;
    auto alloc = [&](size_t bytes) -> void* {
        void* p = ws + off;
        off += (bytes + 255) & ~(size_t)255;
        return p;
    };
    u16*   qkvw_b = (u16*)alloc(3072ull * 1024 * 2);
    u16*   outw_b = (u16*)alloc(1024ull * 1024 * 2);
    u16*   upw_b  = (u16*)alloc(4096ull * 1024 * 2);
    u16*   dnw_b  = (u16*)alloc(1024ull * 4096 * 2);
    u16*   h_b    = (u16*)alloc(4096ull * 1024 * 2);
    u16*   qkv_o  = (u16*)alloc(4096ull * 3072 * 2);
    u16*   ctx    = (u16*)alloc(4096ull * 1024 * 2);
    float* x2     = (float*)alloc(4096ull * 1024 * 4);
    u16*   u      = (u16*)alloc(4096ull * 4096 * 2);
    // vt aliases u: vt live [qkv-gemm .. attn_k]; u live [ffn-up .. ffn-down].
    u16*   vt     = u;

    hipFuncSetAttribute((const void*)&gemm256_k<16, 0>,
                        hipFuncAttributeMaxDynamicSharedMemorySize, 131072);
    hipFuncSetAttribute((const void*)&gemm256_k<16, 2>,
                        hipFuncAttributeMaxDynamicSharedMemorySize, 131072);
    hipFuncSetAttribute((const void*)&gemm128w8_k<16>,
                        hipFuncAttributeMaxDynamicSharedMemorySize, 131072);
    hipFuncSetAttribute((const void*)&gemm128w8_k<64>,
                        hipFuncAttributeMaxDynamicSharedMemorySize, 131072);

    // fused: weight converts (12288 blocks) + LN1 (4096 blocks) in ONE launch
    cvtln_k<<<16384, 256, 0, stream>>>(qkv_w, out_w, up_w, down_w,
                                       qkvw_b, outw_b, upw_b, dnw_b,
                                       x, h_b, n1s, n1b);

    // --- attention sublayer ---
    gemm256_k<16, 0><<<dim3(16, 12), 512, 131072, stream>>>(h_b, qkvw_b, qkv_o, vt,
                                                            4096, 3072, 1024);
    attn_k<<<dim3(32, 16), 512, 0, stream>>>(qkv_o, vt, ctx);
    // proj: x2 = x + ctx@outw^T (8-wave, 4-slot ring)
    gemm128w8_k<16><<<dim3(32, 8), 512, 131072, stream>>>(ctx, outw_b, x2, x,
                                                          4096, 1024, 1024);

    // --- FFN sublayer ---
    ln_k<<<4096, 256, 0, stream>>>(x2, h_b, n2s, n2b);
    gemm256_k<16, 2><<<dim3(16, 16), 512, 131072, stream>>>(h_b, upw_b, u, nullptr,
                                                            4096, 4096, 1024);
    // down: out = x2 + u@dnw^T (8-wave, 4-slot ring, direct)
    gemm128w8_k<64><<<dim3(32, 8), 512, 131072, stream>>>(u, dnw_b, out, x2,
                                                          4096, 1024, 4096);
}